// Round 1
// baseline (920.858 us; speedup 1.0000x reference)
//
#include <hip/hip_runtime.h>

#define NN 50000
#define NE 800000
#define F 256
#define NHEADS 8

// ---------------- CSR build (dst-sorted) ----------------
__global__ void k_zero_int(int* __restrict__ p, int n) {
  int i = blockIdx.x * blockDim.x + threadIdx.x;
  if (i < n) p[i] = 0;
}

__global__ void k_hist(const int* __restrict__ dst, int* __restrict__ counts, int e) {
  int i = blockIdx.x * blockDim.x + threadIdx.x;
  if (i < e) atomicAdd(&counts[dst[i]], 1);
}

// single-block exclusive scan of counts[0..n) -> off[0..n]; zeroes counts for reuse as cursor
__global__ __launch_bounds__(1024) void k_scan(int* __restrict__ counts, int* __restrict__ off, int n) {
  __shared__ int buf[1024];
  __shared__ int base_s;
  int tid = threadIdx.x;
  if (tid == 0) base_s = 0;
  __syncthreads();
  for (int start = 0; start < n; start += 1024) {
    int i = start + tid;
    int v = (i < n) ? counts[i] : 0;
    buf[tid] = v;
    __syncthreads();
    for (int d = 1; d < 1024; d <<= 1) {
      int t = (tid >= d) ? buf[tid - d] : 0;
      __syncthreads();
      buf[tid] += t;
      __syncthreads();
    }
    if (i < n) { off[i] = base_s + buf[tid] - v; counts[i] = 0; }
    __syncthreads();
    if (tid == 1023) base_s += buf[1023];
    __syncthreads();
  }
  if (tid == 0) off[n] = base_s;
}

__global__ void k_scatter(const int* __restrict__ src, const int* __restrict__ dst,
                          const int* __restrict__ off, int* __restrict__ cursor,
                          int* __restrict__ csr_src, int e) {
  int i = blockIdx.x * blockDim.x + threadIdx.x;
  if (i < e) {
    int d = dst[i];
    int p = atomicAdd(&cursor[d], 1);
    csr_src[off[d] + p] = src[i];
  }
}

// ---------------- f32 GEMM: C[M,256] = A[M,256] @ B[256,256] ----------------
// 64x64 tile, BK=16, 256 threads, 4x4 per thread
__global__ __launch_bounds__(256) void k_gemm(
    const float* __restrict__ A, const float* __restrict__ B,
    float* __restrict__ C, int M)
{
  __shared__ float As[16][64 + 4];  // [k][m]
  __shared__ float Bs[16][64 + 4];  // [k][n]
  const int tid = threadIdx.x;
  const int bm = blockIdx.x * 64;
  const int bn = blockIdx.y * 64;
  const int ty = tid >> 4;       // 0..15
  const int tx = tid & 15;       // 0..15
  // A-load indices: 64 rows x 16 k, float4 along k
  const int lr = tid >> 2;            // 0..63
  const int lk = (tid & 3) << 2;      // 0,4,8,12
  // B-load indices: 16 k-rows x 64 cols, float4 along col
  const int brk = tid >> 4;           // 0..15
  const int bc  = (tid & 15) << 2;    // 0..60
  float acc[4][4] = {};
  for (int k0 = 0; k0 < 256; k0 += 16) {
    float4 av = make_float4(0.f, 0.f, 0.f, 0.f);
    const int arow = bm + lr;
    if (arow < M) av = *reinterpret_cast<const float4*>(&A[(size_t)arow * F + k0 + lk]);
    As[lk + 0][lr] = av.x;
    As[lk + 1][lr] = av.y;
    As[lk + 2][lr] = av.z;
    As[lk + 3][lr] = av.w;
    const float4 bv = *reinterpret_cast<const float4*>(&B[(size_t)(k0 + brk) * F + bn + bc]);
    *reinterpret_cast<float4*>(&Bs[brk][bc]) = bv;
    __syncthreads();
#pragma unroll
    for (int kk = 0; kk < 16; ++kk) {
      float af[4], bf[4];
#pragma unroll
      for (int r = 0; r < 4; ++r) af[r] = As[kk][ty * 4 + r];
#pragma unroll
      for (int c = 0; c < 4; ++c) bf[c] = Bs[kk][tx * 4 + c];
#pragma unroll
      for (int r = 0; r < 4; ++r)
#pragma unroll
        for (int c = 0; c < 4; ++c)
          acc[r][c] += af[r] * bf[c];
    }
    __syncthreads();
  }
#pragma unroll
  for (int r = 0; r < 4; ++r) {
    const int row = bm + ty * 4 + r;
    if (row < M) {
      float4 o = make_float4(acc[r][0], acc[r][1], acc[r][2], acc[r][3]);
      *reinterpret_cast<float4*>(&C[(size_t)row * F + bn + tx * 4]) = o;
    }
  }
}

// ---------------- el/er: per (node, head) dot of h-row-slice with al/ar ----------------
__global__ void k_elr(const float* __restrict__ h, const float* __restrict__ al,
                      const float* __restrict__ ar, float* __restrict__ el,
                      float* __restrict__ er) {
  int i = blockIdx.x * blockDim.x + threadIdx.x;  // i in [0, NN*8)
  if (i >= NN * NHEADS) return;
  const int hd = i & 7;
  const float* hp = &h[(size_t)i * 32];
  float sl = 0.f, sr = 0.f;
#pragma unroll
  for (int d = 0; d < 32; d += 4) {
    float4 hv = *reinterpret_cast<const float4*>(&hp[d]);
    float4 av = *reinterpret_cast<const float4*>(&al[hd * 32 + d]);
    float4 rv = *reinterpret_cast<const float4*>(&ar[hd * 32 + d]);
    sl += hv.x * av.x + hv.y * av.y + hv.z * av.z + hv.w * av.w;
    sr += hv.x * rv.x + hv.y * rv.y + hv.z * rv.z + hv.w * rv.w;
  }
  el[i] = sl;
  er[i] = sr;
}

// ---------------- aggregation: one wave per dst node ----------------
__global__ __launch_bounds__(256) void k_agg(
    const float* __restrict__ h, const float* __restrict__ el,
    const float* __restrict__ er, const int* __restrict__ off,
    const int* __restrict__ csr_src, const float* __restrict__ bias,
    float* __restrict__ y, int apply_act)
{
  __shared__ float a_lds[4][64][NHEADS];
  __shared__ int s_lds[4][64];
  const int wave = threadIdx.x >> 6;
  const int lane = threadIdx.x & 63;
  const int n = blockIdx.x * 4 + wave;
  if (n >= NN) return;
  const int o0 = off[n], o1 = off[n + 1];

  float ern[NHEADS];
#pragma unroll
  for (int t = 0; t < NHEADS; ++t) ern[t] = er[n * NHEADS + t];

  // pass 1: per-head max over incoming edges
  float m[NHEADS];
#pragma unroll
  for (int t = 0; t < NHEADS; ++t) m[t] = -1e30f;
  for (int i = o0 + lane; i < o1; i += 64) {
    const int s = csr_src[i];
#pragma unroll
    for (int t = 0; t < NHEADS; ++t) {
      float e = el[s * NHEADS + t] + ern[t];
      e = e > 0.f ? e : 0.2f * e;
      m[t] = fmaxf(m[t], e);
    }
  }
#pragma unroll
  for (int t = 0; t < NHEADS; ++t) {
#pragma unroll
    for (int d = 32; d >= 1; d >>= 1)
      m[t] = fmaxf(m[t], __shfl_xor(m[t], d, 64));
  }

  // pass 2: per-head sum of exp
  float ssum[NHEADS];
#pragma unroll
  for (int t = 0; t < NHEADS; ++t) ssum[t] = 0.f;
  for (int i = o0 + lane; i < o1; i += 64) {
    const int s = csr_src[i];
#pragma unroll
    for (int t = 0; t < NHEADS; ++t) {
      float e = el[s * NHEADS + t] + ern[t];
      e = e > 0.f ? e : 0.2f * e;
      ssum[t] += __expf(e - m[t]);
    }
  }
#pragma unroll
  for (int t = 0; t < NHEADS; ++t) {
#pragma unroll
    for (int d = 32; d >= 1; d >>= 1)
      ssum[t] += __shfl_xor(ssum[t], d, 64);
  }
  float inv[NHEADS];
#pragma unroll
  for (int t = 0; t < NHEADS; ++t) inv[t] = ssum[t] > 0.f ? 1.f / ssum[t] : 0.f;

  // pass 3: weighted aggregation; lane owns 4 contiguous columns (one head)
  const int c0 = lane * 4;
  const int myh = lane >> 3;
  float4 acc = make_float4(0.f, 0.f, 0.f, 0.f);
  for (int start = o0; start < o1; start += 64) {
    const int idx = start + lane;
    if (idx < o1) {
      const int s = csr_src[idx];
      s_lds[wave][lane] = s;
#pragma unroll
      for (int t = 0; t < NHEADS; ++t) {
        float e = el[s * NHEADS + t] + ern[t];
        e = e > 0.f ? e : 0.2f * e;
        a_lds[wave][lane][t] = __expf(e - m[t]) * inv[t];
      }
    }
    // same-wave LDS RAW: DS ops execute in order per wave; stop compiler motion
    asm volatile("s_waitcnt lgkmcnt(0)" ::: "memory");
    __builtin_amdgcn_sched_barrier(0);
    const int cnt = min(64, o1 - start);
    for (int k = 0; k < cnt; ++k) {
      const int s = s_lds[wave][k];
      const float a = a_lds[wave][k][myh];
      const float4 hv = *reinterpret_cast<const float4*>(&h[(size_t)s * F + c0]);
      acc.x += a * hv.x;
      acc.y += a * hv.y;
      acc.z += a * hv.z;
      acc.w += a * hv.w;
    }
    __builtin_amdgcn_sched_barrier(0);
  }
  float4 o;
  o.x = acc.x + bias[c0 + 0];
  o.y = acc.y + bias[c0 + 1];
  o.z = acc.z + bias[c0 + 2];
  o.w = acc.w + bias[c0 + 3];
  if (apply_act) {
    o.x = o.x > 0.f ? o.x : 0.01f * o.x;
    o.y = o.y > 0.f ? o.y : 0.01f * o.y;
    o.z = o.z > 0.f ? o.z : 0.01f * o.z;
    o.w = o.w > 0.f ? o.w : 0.01f * o.w;
  }
  *reinterpret_cast<float4*>(&y[(size_t)n * F + c0]) = o;
}

extern "C" void kernel_launch(void* const* d_in, const int* in_sizes, int n_in,
                              void* d_out, int out_size, void* d_ws, size_t ws_size,
                              hipStream_t stream) {
  const float* x   = (const float*)d_in[0];
  const int*   src = (const int*)d_in[1];
  const int*   dst = (const int*)d_in[2];
  const float* W   = (const float*)d_in[3];
  const float* al  = (const float*)d_in[4];
  const float* ar  = (const float*)d_in[5];
  const float* b   = (const float*)d_in[6];
  float* out = (float*)d_out;

  char* ws = (char*)d_ws;
  auto take = [&](size_t bytes) {
    char* p = ws;
    ws += (bytes + 255) & ~(size_t)255;
    return p;
  };
  int*   off     = (int*)take((NN + 1) * sizeof(int));
  int*   cursor  = (int*)take(NN * sizeof(int));
  int*   csr_src = (int*)take(NE * sizeof(int));
  float* el      = (float*)take((size_t)NN * NHEADS * sizeof(float));
  float* er      = (float*)take((size_t)NN * NHEADS * sizeof(float));
  float* h       = (float*)take((size_t)NN * F * sizeof(float));

  // CSR build (per call; deterministic up to float-sum order within a node)
  k_zero_int<<<(NN + 255) / 256, 256, 0, stream>>>(cursor, NN);
  k_hist<<<(NE + 255) / 256, 256, 0, stream>>>(dst, cursor, NE);
  k_scan<<<1, 1024, 0, stream>>>(cursor, off, NN);
  k_scatter<<<(NE + 255) / 256, 256, 0, stream>>>(src, dst, off, cursor, csr_src, NE);

  dim3 ggrid((NN + 63) / 64, F / 64);
  for (int l = 0; l < 3; ++l) {
    const float* xin = (l == 0) ? x : out;
    k_gemm<<<ggrid, 256, 0, stream>>>(xin, W + (size_t)l * F * F, h, NN);
    k_elr<<<(NN * NHEADS + 255) / 256, 256, 0, stream>>>(h, al + l * F, ar + l * F, el, er);
    k_agg<<<NN / 4, 256, 0, stream>>>(h, el, er, off, csr_src, b + l * F, out, (l < 2) ? 1 : 0);
  }
}